// Round 2
// baseline (643.053 us; speedup 1.0000x reference)
//
#include <hip/hip_runtime.h>
#include <hip/hip_bf16.h>

#define C 128
#define L 16384
#define B 8
#define MID 32
#define NBL (B * L)

typedef unsigned short ushort_t;
typedef __attribute__((ext_vector_type(8))) short s8v;   // 8 bf16
typedef __attribute__((ext_vector_type(4))) float f4v;   // 4 fp32

__device__ __forceinline__ unsigned short f2bf(float f) {
    union { float f; unsigned int u; } a; a.f = f;
    unsigned int u = a.u;
    return (unsigned short)((u + 0x7fffu + ((u >> 16) & 1u)) >> 16);
}

__device__ __forceinline__ float bf2f(short h) {
    return __uint_as_float(((unsigned int)(unsigned short)h) << 16);
}

__device__ __forceinline__ void unpack8(s8v v, float* f) {
#pragma unroll
    for (int j = 0; j < 8; j++) f[j] = bf2f(v[j]);
}

__device__ __forceinline__ s8v pack8(const float* f) {
    s8v v;
#pragma unroll
    for (int j = 0; j < 8; j++) v[j] = (short)f2bf(f[j]);
    return v;
}

__device__ __forceinline__ void ld8f(const float* p, float* f) {
    float4 a = *(const float4*)p;
    float4 b = *(const float4*)(p + 4);
    f[0] = a.x; f[1] = a.y; f[2] = a.z; f[3] = a.w;
    f[4] = b.x; f[5] = b.y; f[6] = b.z; f[7] = b.w;
}

// fragment-order index for staged weights: slot in [0,13), o = out channel row, w = col within slot's 32
__device__ __forceinline__ int widx(int slot, int o, int w) {
    return ((slot * 8 + (o >> 4)) * 64 + (w >> 3) * 16 + (o & 15)) * 8 + (w & 7);
}

// ------------------------------------------------ k_cvt: x fp32 [b][c][l] -> xb bf16 [b][l][c], + gap sums
__global__ __launch_bounds__(256) void k_cvt(const float* __restrict__ x,
                                             ushort_t* __restrict__ xb,
                                             float* __restrict__ gap) {
    __shared__ float xs[64][129];
    const int bid = blockIdx.x;
    const int b = bid >> 8;
    const int l0 = (bid & 255) * 64;
    const int tid = threadIdx.x;
    const int c = tid >> 1, h = tid & 1;
    const float* src = x + ((size_t)(b * C + c)) * L + l0 + h * 32;
    float s = 0.f;
#pragma unroll
    for (int j = 0; j < 8; j++) {
        float4 v = *(const float4*)(src + j * 4);
        s += (v.x + v.y) + (v.z + v.w);
        int lb = h * 32 + j * 4;
        xs[lb + 0][c] = v.x; xs[lb + 1][c] = v.y;
        xs[lb + 2][c] = v.z; xs[lb + 3][c] = v.w;
    }
    s += __shfl_xor(s, 1);
    if (h == 0) atomicAdd(&gap[b * C + c], s);
    __syncthreads();
    const int l = tid & 63, quarter = tid >> 6, cb = quarter * 32;
    union { ushort_t hh[32]; uint4 q[4]; } u;
#pragma unroll
    for (int k = 0; k < 32; k++) u.hh[k] = f2bf(xs[l][cb + k]);
    uint4* dst = (uint4*)(xb + ((size_t)(b * L + l0 + l)) * C + cb);
#pragma unroll
    for (int k = 0; k < 4; k++) dst[k] = u.q[k];
}

// ------------------------------------------------ k_prep_b: gap -> a (mlp1 coefs), pv = p0/p1/p2 per batch
// s1[l] = p0.x[l-1] + p1.x[l] + p2.x[l+1], pk[j] = sum_c gw_c * wcd[3c+k] * Wci[c][j]
__global__ __launch_bounds__(128) void k_prep_b(const float* __restrict__ gap,
                                                const float* __restrict__ w1,
                                                const float* __restrict__ Wco,
                                                const float* __restrict__ wcd,
                                                const float* __restrict__ Wci,
                                                float* __restrict__ a,
                                                float* __restrict__ pv) {
    int b = blockIdx.x, c = threadIdx.x;
    __shared__ float gl[C];
    __shared__ float red[C];
    __shared__ float gws[C];
    float v = gap[b * C + c] * (1.f / (float)L);
    red[c] = v * v;
    __syncthreads();
    for (int w = 64; w > 0; w >>= 1) {
        if (c < w) red[c] += red[c + w];
        __syncthreads();
    }
    float nrm = fmaxf(sqrtf(red[0]), 1e-12f);
    gl[c] = v / nrm;
    __syncthreads();
    if (c < MID) {
        float s = 0.f;
        for (int k = 0; k < C; k++) s = fmaf(w1[c * C + k], gl[k], s);
        a[b * MID + c] = s;
    }
    {
        float s = 0.f;
        for (int k = 0; k < C; k++) s = fmaf(gl[k], Wco[k * C + c], s);
        gws[c] = s;
    }
    __syncthreads();
    float p0 = 0.f, p1 = 0.f, p2 = 0.f;
    for (int cc = 0; cc < C; cc++) {
        float wv = Wci[cc * C + c];
        float g = gws[cc];
        p0 = fmaf(g * wcd[3 * cc], wv, p0);
        p1 = fmaf(g * wcd[3 * cc + 1], wv, p1);
        p2 = fmaf(g * wcd[3 * cc + 2], wv, p2);
    }
    pv[b * 384 + c] = p0;
    pv[b * 384 + 128 + c] = p1;
    pv[b * 384 + 256 + c] = p2;
}

// ------------------------------------------------ k_prep_w: compose weights, write in MFMA-fragment order
// slots 0-3: A1 = Wct*diag(k1)*Win ; 4-7: AS = Wct*diag(kS)*Win ; 8-11: Wproj ; 12: Ws = Wproj@w2
__global__ __launch_bounds__(128) void k_prep_w(const float* __restrict__ Win,
                                                const float* __restrict__ Wproj,
                                                const float* __restrict__ Wout,
                                                const float* __restrict__ w2,
                                                const float* __restrict__ b2,
                                                const float* __restrict__ wds,
                                                ushort_t* __restrict__ Wf,
                                                float* __restrict__ bp) {
    int o = blockIdx.x, c = threadIdx.x;
    __shared__ float pr[C];
    __shared__ float wct[C];
    pr[c] = Wproj[o * C + c];
    __syncthreads();
    {
        float s = 0.f;
        for (int k = 0; k < C; k++) s = fmaf(pr[k], Wout[k * C + c], s);
        wct[c] = s;
    }
    __syncthreads();
    float a1 = 0.f, as = 0.f;
    for (int cc = 0; cc < C; cc++) {
        float w = wct[cc];
        float win = Win[cc * C + c];
        a1 = fmaf(w * wds[3 * cc + 1], win, a1);
        as = fmaf(w * (0.25f * (wds[3 * cc] + wds[3 * cc + 2])), win, as);
    }
    const int slot = c >> 5, wi = c & 31;
    Wf[widx(slot, o, wi)] = f2bf(a1);
    Wf[widx(4 + slot, o, wi)] = f2bf(as);
    Wf[widx(8 + slot, o, wi)] = f2bf(pr[c]);
    if (c < MID) {
        float s2 = 0.f;
        for (int k = 0; k < C; k++) s2 = fmaf(pr[k], w2[k * MID + c], s2);
        Wf[widx(12, o, c)] = f2bf(s2);
    }
    if (c == 0) {
        float s3 = 0.f;
        for (int k = 0; k < C; k++) s3 = fmaf(pr[k], b2[k], s3);
        bp[o] = s3;
    }
}

// ------------------------------------------------ k_fused: out = A1@xC + AS@(4 nbrs) + Wproj@yd + Ws@silu + bp
// grid 512 = 8 b * 64 y-pairs; 1024 threads = 16 waves, each wave covers 16 l (2 image rows per block)
__global__ __launch_bounds__(1024, 4) void k_fused(const ushort_t* __restrict__ xb,
                                                   const ushort_t* __restrict__ Wf,
                                                   const float* __restrict__ pv,
                                                   const float* __restrict__ a,
                                                   const float* __restrict__ b1,
                                                   const float* __restrict__ pdw,
                                                   const float* __restrict__ bp,
                                                   float* __restrict__ outp) {
    __shared__ ushort_t wlf[53248];           // 106,496 B, fragment-ordered weights
    const int tid = threadIdx.x;
    int bid = blockIdx.x;
    bid = (bid & 7) * 64 + (bid >> 3);        // bijective XCD swizzle: XCD k owns batch k
    const int b = bid >> 6;
    const int y0 = (bid & 63) << 1;

    // stage Wf: 6656 uint4 over 1024 threads
#pragma unroll
    for (int i = 0; i < 7; i++) {
        int idx = tid + i * 1024;
        if (idx < 6656) ((uint4*)wlf)[idx] = ((const uint4*)Wf)[idx];
    }

    const int wave = tid >> 6, lane = tid & 63;
    const int n = lane & 15, q = lane >> 4;
    const int y = y0 + (wave >> 3);
    const int xg = (wave & 7) * 16 + n;
    const int l = y * 128 + xg;
    const size_t rb = (size_t)b * L;

    const int rL = (l > 0) ? (l - 1) : -1;
    const int rR = (l < L - 1) ? (l + 1) : -1;
    const int rU = (y > 0) ? (l - 128) : ((xg > 0) ? (16256 + xg - 1) : -1);
    const int rD = (y < 127) ? (l + 128) : ((xg < 127) ? (xg + 1) : -1);
    const int sL = (xg > 0) ? (l - 1) : (l + 1);
    const int sR = (xg < 127) ? (l + 1) : (l - 1);
    const int sU = (y > 0) ? (l - 128) : (l + 128);
    const int sD = (y < 127) ? (l + 128) : (l - 128);

    const float dwt4 = pdw[0] * 0.25f;
    const ushort_t* xrow = xb + (rb + l) * C;

    s8v fxc[4], fyd[4];
    float s1 = 0.f;
#pragma unroll
    for (int ks = 0; ks < 4; ks++) {
        const int c0 = ks * 32 + q * 8;
        s8v vc = *(const s8v*)(xrow + c0);
        fxc[ks] = vc;
        float xc[8]; unpack8(vc, xc);
        float xsl[8], xsr[8], xsu[8], xsd[8];
        unpack8(*(const s8v*)(xb + (rb + sL) * C + c0), xsl);
        unpack8(*(const s8v*)(xb + (rb + sR) * C + c0), xsr);
        unpack8(*(const s8v*)(xb + (rb + sU) * C + c0), xsu);
        unpack8(*(const s8v*)(xb + (rb + sD) * C + c0), xsd);
        float yd8[8];
#pragma unroll
        for (int j = 0; j < 8; j++) {
            float d = fabsf(xc[j] - xsl[j]) + fabsf(xc[j] - xsr[j]) +
                      fabsf(xc[j] - xsu[j]) + fabsf(xc[j] - xsd[j]);
            yd8[j] = fmaf(dwt4, d, xc[j]);
        }
        fyd[ks] = pack8(yd8);

        // s1 contribution (zero-padded sequence neighbors rL/rR)
        const int rlc = (rL >= 0) ? rL : 0;
        const int rrc = (rR >= 0) ? rR : 0;
        float xl1[8], xr1[8];
        unpack8(*(const s8v*)(xb + (rb + rlc) * C + c0), xl1);
        unpack8(*(const s8v*)(xb + (rb + rrc) * C + c0), xr1);
        if (rL < 0) {
#pragma unroll
            for (int j = 0; j < 8; j++) xl1[j] = 0.f;
        }
        if (rR < 0) {
#pragma unroll
            for (int j = 0; j < 8; j++) xr1[j] = 0.f;
        }
        float p0v[8], p1v[8], p2v[8];
        ld8f(pv + b * 384 + c0, p0v);
        ld8f(pv + b * 384 + 128 + c0, p1v);
        ld8f(pv + b * 384 + 256 + c0, p2v);
#pragma unroll
        for (int j = 0; j < 8; j++) {
            s1 = fmaf(p1v[j], xc[j], s1);
            s1 = fmaf(p0v[j], xl1[j], s1);
            s1 = fmaf(p2v[j], xr1[j], s1);
        }
    }
    s1 += __shfl_xor(s1, 16);
    s1 += __shfl_xor(s1, 32);

    s8v fs;
    {
        float av[8], bv[8];
        ld8f(a + b * MID + q * 8, av);
        ld8f(b1 + q * 8, bv);
#pragma unroll
        for (int j = 0; j < 8; j++) {
            float pre = fmaf(av[j], s1, bv[j]);
            fs[j] = (short)f2bf(pre / (1.f + __expf(-pre)));
        }
    }

    f4v acc[8];
#pragma unroll
    for (int i = 0; i < 8; i++) acc[i] = (f4v){0.f, 0.f, 0.f, 0.f};

    __syncthreads();

#define AF(slot, mt) (*(const s8v*)(wlf + ((((slot) * 8 + (mt)) * 64 + lane) * 8)))

    // slots 0-3: A1 @ xC
#pragma unroll
    for (int ks = 0; ks < 4; ks++)
#pragma unroll
        for (int mt = 0; mt < 8; mt++)
            acc[mt] = __builtin_amdgcn_mfma_f32_16x16x32_bf16(AF(ks, mt), fxc[ks], acc[mt], 0, 0, 0);

    // slots 4-7: AS @ each zero-padded stencil neighbor (raw bf16 feed, no VALU)
    const int nbr[4] = {rL, rR, rU, rD};
#pragma unroll
    for (int t = 0; t < 4; t++) {
        const int r = nbr[t];
        const int rc = (r >= 0) ? r : 0;
        s8v fn[4];
#pragma unroll
        for (int ks = 0; ks < 4; ks++) {
            s8v v = *(const s8v*)(xb + (rb + rc) * C + ks * 32 + q * 8);
            if (r < 0) {
#pragma unroll
                for (int j = 0; j < 8; j++) v[j] = 0;
            }
            fn[ks] = v;
        }
#pragma unroll
        for (int ks = 0; ks < 4; ks++)
#pragma unroll
            for (int mt = 0; mt < 8; mt++)
                acc[mt] = __builtin_amdgcn_mfma_f32_16x16x32_bf16(AF(4 + ks, mt), fn[ks], acc[mt], 0, 0, 0);
    }

    // slots 8-11: Wproj @ yd
#pragma unroll
    for (int ks = 0; ks < 4; ks++)
#pragma unroll
        for (int mt = 0; mt < 8; mt++)
            acc[mt] = __builtin_amdgcn_mfma_f32_16x16x32_bf16(AF(8 + ks, mt), fyd[ks], acc[mt], 0, 0, 0);

    // slot 12: Ws @ silu
#pragma unroll
    for (int mt = 0; mt < 8; mt++)
        acc[mt] = __builtin_amdgcn_mfma_f32_16x16x32_bf16(AF(12, mt), fs, acc[mt], 0, 0, 0);

#undef AF

    // epilogue: bias + store
#pragma unroll
    for (int mt = 0; mt < 8; mt++) {
        const int o0 = mt * 16 + q * 4;
        float4 bv4 = *(const float4*)(bp + o0);
        float ba[4] = {bv4.x, bv4.y, bv4.z, bv4.w};
#pragma unroll
        for (int i = 0; i < 4; i++) {
            outp[((size_t)(b * C + o0 + i)) * L + l] = acc[mt][i] + ba[i];
        }
    }
}

// ------------------------------------------------ BN
__global__ __launch_bounds__(256) void k_bnstats2(const float* __restrict__ outp,
                                                  float* __restrict__ stats) {
    const int bo = blockIdx.x;
    const int o = bo & (C - 1);
    const float4* p = (const float4*)(outp + (size_t)bo * L);
    float s = 0.f, sq = 0.f;
    for (int i = threadIdx.x; i < L / 4; i += 256) {
        float4 v = p[i];
        s += (v.x + v.y) + (v.z + v.w);
        sq += v.x * v.x + v.y * v.y + v.z * v.z + v.w * v.w;
    }
    __shared__ float rs[256], rq[256];
    rs[threadIdx.x] = s; rq[threadIdx.x] = sq;
    __syncthreads();
    for (int w = 128; w > 0; w >>= 1) {
        if (threadIdx.x < w) {
            rs[threadIdx.x] += rs[threadIdx.x + w];
            rq[threadIdx.x] += rq[threadIdx.x + w];
        }
        __syncthreads();
    }
    if (threadIdx.x == 0) {
        atomicAdd(&stats[o], rs[0]);
        atomicAdd(&stats[C + o], rq[0]);
    }
}

__global__ void k_bnfin(const float* __restrict__ stats, const float* __restrict__ gamma,
                        const float* __restrict__ beta, float* __restrict__ scsh) {
    int o = threadIdx.x;
    float n = (float)NBL;
    float mu = stats[o] / n;
    float var = stats[C + o] / n - mu * mu;
    float sc = gamma[o] * rsqrtf(var + 1e-5f);
    scsh[o] = sc;
    scsh[C + o] = fmaf(-mu, sc, beta[o]);
}

__global__ __launch_bounds__(256) void k_bnapply(float* __restrict__ outp,
                                                 const float* __restrict__ scsh) {
    int bo = blockIdx.x;
    int o = bo & (C - 1);
    float sc = scsh[o], sh = scsh[C + o];
    float4* p = (float4*)(outp + (size_t)bo * L);
    for (int i = threadIdx.x; i < L / 4; i += 256) {
        float4 v = p[i];
        v.x = fmaf(v.x, sc, sh);
        v.y = fmaf(v.y, sc, sh);
        v.z = fmaf(v.z, sc, sh);
        v.w = fmaf(v.w, sc, sh);
        p[i] = v;
    }
}

// ------------------------------------------------ launch
extern "C" void kernel_launch(void* const* d_in, const int* in_sizes, int n_in,
                              void* d_out, int out_size, void* d_ws, size_t ws_size,
                              hipStream_t stream) {
    const float* x = (const float*)d_in[0];
    const float* Win = (const float*)d_in[1];
    const float* wds = (const float*)d_in[2];
    const float* Wout = (const float*)d_in[3];
    const float* Wci = (const float*)d_in[4];
    const float* wcd = (const float*)d_in[5];
    const float* Wco = (const float*)d_in[6];
    const float* w1 = (const float*)d_in[7];
    const float* b1 = (const float*)d_in[8];
    const float* w2 = (const float*)d_in[9];
    const float* b2 = (const float*)d_in[10];
    const float* pdw = (const float*)d_in[11];
    const float* gamma = (const float*)d_in[12];
    const float* beta = (const float*)d_in[13];
    const float* Wproj = (const float*)d_in[14];

    char* wsb = (char*)d_ws;
    ushort_t* xb = (ushort_t*)wsb;                       // 33,554,432 B
    ushort_t* Wf = (ushort_t*)(wsb + 33554432);          // 106,496 B (fragment-ordered weights)
    char* S = wsb + 176160768;
    float* gap  = (float*)(S + 0);        // 1024 B
    float* stats= (float*)(S + 4096);     // 1024 B
    float* scsh = (float*)(S + 5120);     // 1024 B
    float* a    = (float*)(S + 6144);     // 1024 B
    float* bp   = (float*)(S + 8192);     // 512 B
    float* pv   = (float*)(S + 12288);    // 12,288 B (8 b * 3 * 128)
    float* outp = (float*)d_out;

    hipMemsetAsync(S, 0, 5120, stream);  // gap + stats
    k_cvt<<<2048, 256, 0, stream>>>(x, xb, gap);
    k_prep_b<<<8, 128, 0, stream>>>(gap, w1, Wco, wcd, Wci, a, pv);
    k_prep_w<<<128, 128, 0, stream>>>(Win, Wproj, Wout, w2, b2, wds, Wf, bp);
    k_fused<<<512, 1024, 0, stream>>>(xb, Wf, pv, a, b1, pdw, bp, outp);
    k_bnstats2<<<1024, 256, 0, stream>>>(outp, stats);
    k_bnfin<<<1, 128, 0, stream>>>(stats, gamma, beta, scsh);
    k_bnapply<<<1024, 256, 0, stream>>>(outp, scsh);
}

// Round 3
// 356.349 us; speedup vs baseline: 1.8046x; 1.8046x over previous
//
#include <hip/hip_runtime.h>
#include <hip/hip_bf16.h>

#define C 128
#define L 16384
#define B 8
#define MID 32
#define NBL (B * L)

typedef unsigned short ushort_t;
typedef __attribute__((ext_vector_type(8))) short s8v;   // 8 bf16
typedef __attribute__((ext_vector_type(4))) float f4v;   // 4 fp32
typedef __attribute__((ext_vector_type(8))) float f8v;   // 8 fp32

__device__ __forceinline__ unsigned short f2bf(float f) {
    union { float f; unsigned int u; } a; a.f = f;
    unsigned int u = a.u;
    return (unsigned short)((u + 0x7fffu + ((u >> 16) & 1u)) >> 16);
}

// value-style helpers: no address-taken locals, pure register code
__device__ __forceinline__ f8v unp8(s8v v) {
    f8v f;
#pragma unroll
    for (int j = 0; j < 8; j++) f[j] = __uint_as_float(((unsigned int)(unsigned short)v[j]) << 16);
    return f;
}

__device__ __forceinline__ s8v pk8(f8v f) {
    s8v v;
#pragma unroll
    for (int j = 0; j < 8; j++) v[j] = (short)f2bf(f[j]);
    return v;
}

__device__ __forceinline__ f8v ldf8(const float* p) {
    float4 a = *(const float4*)p;
    float4 b = *(const float4*)(p + 4);
    f8v f;
    f[0] = a.x; f[1] = a.y; f[2] = a.z; f[3] = a.w;
    f[4] = b.x; f[5] = b.y; f[6] = b.z; f[7] = b.w;
    return f;
}

// fragment-order index for staged weights: slot in [0,13), o = out channel row, w = col within slot's 32
__device__ __forceinline__ int widx(int slot, int o, int w) {
    return ((slot * 8 + (o >> 4)) * 64 + (w >> 3) * 16 + (o & 15)) * 8 + (w & 7);
}

// ------------------------------------------------ k_cvt: x fp32 [b][c][l] -> xb bf16 [b][l][c], + gap sums
__global__ __launch_bounds__(256) void k_cvt(const float* __restrict__ x,
                                             ushort_t* __restrict__ xb,
                                             float* __restrict__ gap) {
    __shared__ float xs[64][129];
    const int bid = blockIdx.x;
    const int b = bid >> 8;
    const int l0 = (bid & 255) * 64;
    const int tid = threadIdx.x;
    const int c = tid >> 1, h = tid & 1;
    const float* src = x + ((size_t)(b * C + c)) * L + l0 + h * 32;
    float s = 0.f;
#pragma unroll
    for (int j = 0; j < 8; j++) {
        float4 v = *(const float4*)(src + j * 4);
        s += (v.x + v.y) + (v.z + v.w);
        int lb = h * 32 + j * 4;
        xs[lb + 0][c] = v.x; xs[lb + 1][c] = v.y;
        xs[lb + 2][c] = v.z; xs[lb + 3][c] = v.w;
    }
    s += __shfl_xor(s, 1);
    if (h == 0) atomicAdd(&gap[b * C + c], s);
    __syncthreads();
    const int l = tid & 63, quarter = tid >> 6, cb = quarter * 32;
    union { ushort_t hh[32]; uint4 q[4]; } u;
#pragma unroll
    for (int k = 0; k < 32; k++) u.hh[k] = f2bf(xs[l][cb + k]);
    uint4* dst = (uint4*)(xb + ((size_t)(b * L + l0 + l)) * C + cb);
#pragma unroll
    for (int k = 0; k < 4; k++) dst[k] = u.q[k];
}

// ------------------------------------------------ k_prep_b: gap -> a (mlp1 coefs), pv = p0/p1/p2 per batch
__global__ __launch_bounds__(128) void k_prep_b(const float* __restrict__ gap,
                                                const float* __restrict__ w1,
                                                const float* __restrict__ Wco,
                                                const float* __restrict__ wcd,
                                                const float* __restrict__ Wci,
                                                float* __restrict__ a,
                                                float* __restrict__ pv) {
    int b = blockIdx.x, c = threadIdx.x;
    __shared__ float gl[C];
    __shared__ float red[C];
    __shared__ float gws[C];
    float v = gap[b * C + c] * (1.f / (float)L);
    red[c] = v * v;
    __syncthreads();
    for (int w = 64; w > 0; w >>= 1) {
        if (c < w) red[c] += red[c + w];
        __syncthreads();
    }
    float nrm = fmaxf(sqrtf(red[0]), 1e-12f);
    gl[c] = v / nrm;
    __syncthreads();
    if (c < MID) {
        float s = 0.f;
        for (int k = 0; k < C; k++) s = fmaf(w1[c * C + k], gl[k], s);
        a[b * MID + c] = s;
    }
    {
        float s = 0.f;
        for (int k = 0; k < C; k++) s = fmaf(gl[k], Wco[k * C + c], s);
        gws[c] = s;
    }
    __syncthreads();
    float p0 = 0.f, p1 = 0.f, p2 = 0.f;
    for (int cc = 0; cc < C; cc++) {
        float wv = Wci[cc * C + c];
        float g = gws[cc];
        p0 = fmaf(g * wcd[3 * cc], wv, p0);
        p1 = fmaf(g * wcd[3 * cc + 1], wv, p1);
        p2 = fmaf(g * wcd[3 * cc + 2], wv, p2);
    }
    pv[b * 384 + c] = p0;
    pv[b * 384 + 128 + c] = p1;
    pv[b * 384 + 256 + c] = p2;
}

// ------------------------------------------------ k_prep_w: compose weights, write in MFMA-fragment order
// slots 0-3: A1 = Wct*diag(k1)*Win ; 4-7: AS = Wct*diag(kS)*Win ; 8-11: Wproj ; 12: Ws = Wproj@w2
__global__ __launch_bounds__(128) void k_prep_w(const float* __restrict__ Win,
                                                const float* __restrict__ Wproj,
                                                const float* __restrict__ Wout,
                                                const float* __restrict__ w2,
                                                const float* __restrict__ b2,
                                                const float* __restrict__ wds,
                                                ushort_t* __restrict__ Wf,
                                                float* __restrict__ bp) {
    int o = blockIdx.x, c = threadIdx.x;
    __shared__ float pr[C];
    __shared__ float wct[C];
    pr[c] = Wproj[o * C + c];
    __syncthreads();
    {
        float s = 0.f;
        for (int k = 0; k < C; k++) s = fmaf(pr[k], Wout[k * C + c], s);
        wct[c] = s;
    }
    __syncthreads();
    float a1 = 0.f, as = 0.f;
    for (int cc = 0; cc < C; cc++) {
        float w = wct[cc];
        float win = Win[cc * C + c];
        a1 = fmaf(w * wds[3 * cc + 1], win, a1);
        as = fmaf(w * (0.25f * (wds[3 * cc] + wds[3 * cc + 2])), win, as);
    }
    const int slot = c >> 5, wi = c & 31;
    Wf[widx(slot, o, wi)] = f2bf(a1);
    Wf[widx(4 + slot, o, wi)] = f2bf(as);
    Wf[widx(8 + slot, o, wi)] = f2bf(pr[c]);
    if (c < MID) {
        float s2 = 0.f;
        for (int k = 0; k < C; k++) s2 = fmaf(pr[k], w2[k * MID + c], s2);
        Wf[widx(12, o, c)] = f2bf(s2);
    }
    if (c == 0) {
        float s3 = 0.f;
        for (int k = 0; k < C; k++) s3 = fmaf(pr[k], b2[k], s3);
        bp[o] = s3;
    }
}

// ------------------------------------------------ k_fused: out = A1@xC + AS@(4 nbrs) + Wproj@yd + Ws@silu + bp
// grid 1024 = 8 b * 128 y; 1024 threads = 16 waves = 8 l-groups x 2 o-halves.
// Each wave: 16 l, 64 output channels (half), acc[4]. Generation duplicated across the 2 halves (L1-hot).
__global__ __launch_bounds__(1024) __attribute__((amdgpu_waves_per_eu(4, 4)))
void k_fused(const ushort_t* __restrict__ xb,
             const ushort_t* __restrict__ Wf,
             const float* __restrict__ pv,
             const float* __restrict__ a,
             const float* __restrict__ b1,
             const float* __restrict__ pdw,
             const float* __restrict__ bp,
             float* __restrict__ outp) {
    __shared__ ushort_t wlf[53248];           // 106,496 B, fragment-ordered weights
    const int tid = threadIdx.x;
    int bid = blockIdx.x;
    bid = (bid & 7) * 128 + (bid >> 3);       // bijective XCD swizzle: XCD k owns batch k
    const int b = bid >> 7;
    const int y = bid & 127;

    // stage Wf: 6656 uint4 over 1024 threads
#pragma unroll
    for (int i = 0; i < 7; i++) {
        int idx = tid + i * 1024;
        if (idx < 6656) ((uint4*)wlf)[idx] = ((const uint4*)Wf)[idx];
    }

    const int wave = tid >> 6, lane = tid & 63;
    const int half = wave & 1;                // o-half: 0 -> o in [0,64), 1 -> [64,128)
    const int lg = wave >> 1;                 // l-group within the row
    const int n = lane & 15, q = lane >> 4;
    const int xg = lg * 16 + n;
    const int l = y * 128 + xg;
    const size_t rb = (size_t)b * L;

    const int rL = (l > 0) ? (l - 1) : -1;
    const int rR = (l < L - 1) ? (l + 1) : -1;
    const int rU = (y > 0) ? (l - 128) : ((xg > 0) ? (16256 + xg - 1) : -1);
    const int rD = (y < 127) ? (l + 128) : ((xg < 127) ? (xg + 1) : -1);
    const int sL = (xg > 0) ? (l - 1) : (l + 1);
    const int sR = (xg < 127) ? (l + 1) : (l - 1);
    const int sU = (y > 0) ? (l - 128) : (l + 128);
    const int sD = (y < 127) ? (l + 128) : (l - 128);

    const float dwt4 = pdw[0] * 0.25f;
    const ushort_t* xrow = xb + (rb + l) * C;

    s8v fxc[4], fyd[4];
    // ---- gen loop A: central fragment + yd (diff stencil) ----
#pragma unroll
    for (int ks = 0; ks < 4; ks++) {
        const int c0 = ks * 32 + q * 8;
        s8v vc = *(const s8v*)(xrow + c0);
        fxc[ks] = vc;
        f8v xc = unp8(vc);
        f8v dl = unp8(*(const s8v*)(xb + (rb + sL) * C + c0));
        f8v dr = unp8(*(const s8v*)(xb + (rb + sR) * C + c0));
        f8v du = unp8(*(const s8v*)(xb + (rb + sU) * C + c0));
        f8v dd = unp8(*(const s8v*)(xb + (rb + sD) * C + c0));
        f8v yd;
#pragma unroll
        for (int j = 0; j < 8; j++) {
            float d = fabsf(xc[j] - dl[j]) + fabsf(xc[j] - dr[j]) +
                      fabsf(xc[j] - du[j]) + fabsf(xc[j] - dd[j]);
            yd[j] = fmaf(dwt4, d, xc[j]);
        }
        fyd[ks] = pk8(yd);
    }

    // ---- gen loop B: s1 (channel-path scalar) ----
    const int rlc = (rL >= 0) ? rL : 0;
    const int rrc = (rR >= 0) ? rR : 0;
    float s1 = 0.f;
#pragma unroll
    for (int ks = 0; ks < 4; ks++) {
        const int c0 = ks * 32 + q * 8;
        f8v xc = unp8(fxc[ks]);
        f8v xl = unp8(*(const s8v*)(xb + (rb + rlc) * C + c0));
        f8v xr = unp8(*(const s8v*)(xb + (rb + rrc) * C + c0));
        if (rL < 0) {
#pragma unroll
            for (int j = 0; j < 8; j++) xl[j] = 0.f;
        }
        if (rR < 0) {
#pragma unroll
            for (int j = 0; j < 8; j++) xr[j] = 0.f;
        }
        f8v p0 = ldf8(pv + b * 384 + c0);
        f8v p1 = ldf8(pv + b * 384 + 128 + c0);
        f8v p2 = ldf8(pv + b * 384 + 256 + c0);
#pragma unroll
        for (int j = 0; j < 8; j++) {
            s1 = fmaf(p1[j], xc[j], s1);
            s1 = fmaf(p0[j], xl[j], s1);
            s1 = fmaf(p2[j], xr[j], s1);
        }
    }
    s1 += __shfl_xor(s1, 16);
    s1 += __shfl_xor(s1, 32);

    s8v fs;
    {
        f8v av = ldf8(a + b * MID + q * 8);
        f8v bv = ldf8(b1 + q * 8);
#pragma unroll
        for (int j = 0; j < 8; j++) {
            float pre = fmaf(av[j], s1, bv[j]);
            fs[j] = (short)f2bf(pre / (1.f + __expf(-pre)));
        }
    }

    f4v acc[4];
#pragma unroll
    for (int i = 0; i < 4; i++) acc[i] = (f4v){0.f, 0.f, 0.f, 0.f};

    __syncthreads();

#define AF(slot, mtg) (*(const s8v*)(wlf + ((((slot) * 8 + (mtg)) * 64 + lane) * 8)))

    // slots 0-3: A1 @ xC
#pragma unroll
    for (int ks = 0; ks < 4; ks++)
#pragma unroll
        for (int mt = 0; mt < 4; mt++)
            acc[mt] = __builtin_amdgcn_mfma_f32_16x16x32_bf16(AF(ks, half * 4 + mt), fxc[ks], acc[mt], 0, 0, 0);

    // slots 4-7: AS @ each zero-padded stencil neighbor (raw bf16 feed)
#pragma unroll
    for (int t = 0; t < 4; t++) {
        const int r = (t == 0) ? rL : (t == 1) ? rR : (t == 2) ? rU : rD;
        const int rc = (r >= 0) ? r : 0;
        const ushort_t* prow = xb + (rb + rc) * C + q * 8;
#pragma unroll
        for (int ks = 0; ks < 4; ks++) {
            s8v v = *(const s8v*)(prow + ks * 32);
            if (r < 0) {
#pragma unroll
                for (int j = 0; j < 8; j++) v[j] = 0;
            }
#pragma unroll
            for (int mt = 0; mt < 4; mt++)
                acc[mt] = __builtin_amdgcn_mfma_f32_16x16x32_bf16(AF(4 + ks, half * 4 + mt), v, acc[mt], 0, 0, 0);
        }
    }

    // slots 8-11: Wproj @ yd
#pragma unroll
    for (int ks = 0; ks < 4; ks++)
#pragma unroll
        for (int mt = 0; mt < 4; mt++)
            acc[mt] = __builtin_amdgcn_mfma_f32_16x16x32_bf16(AF(8 + ks, half * 4 + mt), fyd[ks], acc[mt], 0, 0, 0);

    // slot 12: Ws @ silu
#pragma unroll
    for (int mt = 0; mt < 4; mt++)
        acc[mt] = __builtin_amdgcn_mfma_f32_16x16x32_bf16(AF(12, half * 4 + mt), fs, acc[mt], 0, 0, 0);

#undef AF

    // epilogue: bias + store
#pragma unroll
    for (int mt = 0; mt < 4; mt++) {
        const int o0 = (half * 4 + mt) * 16 + q * 4;
        float4 bv4 = *(const float4*)(bp + o0);
#pragma unroll
        for (int i = 0; i < 4; i++) {
            float bai = (i == 0) ? bv4.x : (i == 1) ? bv4.y : (i == 2) ? bv4.z : bv4.w;
            outp[((size_t)(b * C + o0 + i)) * L + l] = acc[mt][i] + bai;
        }
    }
}

// ------------------------------------------------ BN
__global__ __launch_bounds__(256) void k_bnstats2(const float* __restrict__ outp,
                                                  float* __restrict__ stats) {
    const int bo = blockIdx.x;
    const int o = bo & (C - 1);
    const float4* p = (const float4*)(outp + (size_t)bo * L);
    float s = 0.f, sq = 0.f;
    for (int i = threadIdx.x; i < L / 4; i += 256) {
        float4 v = p[i];
        s += (v.x + v.y) + (v.z + v.w);
        sq += v.x * v.x + v.y * v.y + v.z * v.z + v.w * v.w;
    }
    __shared__ float rs[256], rq[256];
    rs[threadIdx.x] = s; rq[threadIdx.x] = sq;
    __syncthreads();
    for (int w = 128; w > 0; w >>= 1) {
        if (threadIdx.x < w) {
            rs[threadIdx.x] += rs[threadIdx.x + w];
            rq[threadIdx.x] += rq[threadIdx.x + w];
        }
        __syncthreads();
    }
    if (threadIdx.x == 0) {
        atomicAdd(&stats[o], rs[0]);
        atomicAdd(&stats[C + o], rq[0]);
    }
}

__global__ void k_bnfin(const float* __restrict__ stats, const float* __restrict__ gamma,
                        const float* __restrict__ beta, float* __restrict__ scsh) {
    int o = threadIdx.x;
    float n = (float)NBL;
    float mu = stats[o] / n;
    float var = stats[C + o] / n - mu * mu;
    float sc = gamma[o] * rsqrtf(var + 1e-5f);
    scsh[o] = sc;
    scsh[C + o] = fmaf(-mu, sc, beta[o]);
}

__global__ __launch_bounds__(256) void k_bnapply(float* __restrict__ outp,
                                                 const float* __restrict__ scsh) {
    int bo = blockIdx.x;
    int o = bo & (C - 1);
    float sc = scsh[o], sh = scsh[C + o];
    float4* p = (float4*)(outp + (size_t)bo * L);
    for (int i = threadIdx.x; i < L / 4; i += 256) {
        float4 v = p[i];
        v.x = fmaf(v.x, sc, sh);
        v.y = fmaf(v.y, sc, sh);
        v.z = fmaf(v.z, sc, sh);
        v.w = fmaf(v.w, sc, sh);
        p[i] = v;
    }
}

// ------------------------------------------------ launch
extern "C" void kernel_launch(void* const* d_in, const int* in_sizes, int n_in,
                              void* d_out, int out_size, void* d_ws, size_t ws_size,
                              hipStream_t stream) {
    const float* x = (const float*)d_in[0];
    const float* Win = (const float*)d_in[1];
    const float* wds = (const float*)d_in[2];
    const float* Wout = (const float*)d_in[3];
    const float* Wci = (const float*)d_in[4];
    const float* wcd = (const float*)d_in[5];
    const float* Wco = (const float*)d_in[6];
    const float* w1 = (const float*)d_in[7];
    const float* b1 = (const float*)d_in[8];
    const float* w2 = (const float*)d_in[9];
    const float* b2 = (const float*)d_in[10];
    const float* pdw = (const float*)d_in[11];
    const float* gamma = (const float*)d_in[12];
    const float* beta = (const float*)d_in[13];
    const float* Wproj = (const float*)d_in[14];

    char* wsb = (char*)d_ws;
    ushort_t* xb = (ushort_t*)wsb;                       // 33,554,432 B
    ushort_t* Wf = (ushort_t*)(wsb + 33554432);          // 106,496 B (fragment-ordered weights)
    char* S = wsb + 176160768;
    float* gap  = (float*)(S + 0);        // 1024 B
    float* stats= (float*)(S + 4096);     // 1024 B
    float* scsh = (float*)(S + 5120);     // 1024 B
    float* a    = (float*)(S + 6144);     // 1024 B
    float* bp   = (float*)(S + 8192);     // 512 B
    float* pv   = (float*)(S + 12288);    // 12,288 B (8 b * 3 * 128)
    float* outp = (float*)d_out;

    hipMemsetAsync(S, 0, 5120, stream);  // gap + stats
    k_cvt<<<2048, 256, 0, stream>>>(x, xb, gap);
    k_prep_b<<<8, 128, 0, stream>>>(gap, w1, Wco, wcd, Wci, a, pv);
    k_prep_w<<<128, 128, 0, stream>>>(Win, Wproj, Wout, w2, b2, wds, Wf, bp);
    k_fused<<<1024, 1024, 0, stream>>>(xb, Wf, pv, a, b1, pdw, bp, outp);
    k_bnstats2<<<1024, 256, 0, stream>>>(outp, stats);
    k_bnfin<<<1, 128, 0, stream>>>(stats, gamma, beta, scsh);
    k_bnapply<<<1024, 256, 0, stream>>>(outp, scsh);
}